// Round 1
// baseline (273.257 us; speedup 1.0000x reference)
//
#include <hip/hip_runtime.h>
#include <stdint.h>

#define N_BASES 5
#define C_IN 128
#define C_OUT 128
#define KK 3
#define HWDIM 56
#define WELEM (C_OUT * C_IN * KK * KK) /* 147456 per base */

typedef __attribute__((ext_vector_type(4))) float f32x4;
typedef __attribute__((ext_vector_type(8))) short bf16x8;

__device__ __forceinline__ unsigned short f2bf(float v) {
  union { float f; uint32_t u; } un;
  un.f = v;
  uint32_t r = un.u + 0x7FFFu + ((un.u >> 16) & 1u);
  return (unsigned short)(r >> 16);
}

// ---- kernel 1: c[n] = scales[n] * mean(|w_n|)  (5 blocks, one per base) ----
__global__ __launch_bounds__(256) void absmean_kernel(
    const float* __restrict__ w, const float* __restrict__ scales,
    float* __restrict__ c) {
  int n = blockIdx.x;
  const f32x4* wb = (const f32x4*)(w + (size_t)n * WELEM);
  float s = 0.f;
  for (int i = threadIdx.x; i < WELEM / 4; i += 256) {
    f32x4 v = wb[i];
    s += fabsf(v.x) + fabsf(v.y) + fabsf(v.z) + fabsf(v.w);
  }
  #pragma unroll
  for (int off = 32; off > 0; off >>= 1) s += __shfl_down(s, off);
  __shared__ float red[4];
  int wid = threadIdx.x >> 6;
  if ((threadIdx.x & 63) == 0) red[wid] = s;
  __syncthreads();
  if (threadIdx.x == 0)
    c[n] = scales[n] * ((red[0] + red[1] + red[2] + red[3]) * (1.0f / (float)WELEM));
}

// ---- kernel 2: W_eff[t][o][i] = sum_n c[n]*sign(w[n][o][i][t])  as bf16 ----
__global__ __launch_bounds__(256) void binweight_kernel(
    const float* __restrict__ w, const float* __restrict__ c,
    unsigned short* __restrict__ wq) {
  int f = blockIdx.x * 256 + threadIdx.x;  // f = o*1152 + i*9 + t, f < 147456
  float s = 0.f;
  #pragma unroll
  for (int n = 0; n < N_BASES; ++n) {
    float v = w[n * WELEM + f];
    float cn = c[n];
    s += (v > 0.f) ? cn : ((v < 0.f) ? -cn : 0.f);
  }
  int o = f / 1152;
  int rem = f - o * 1152;
  int i = rem / 9;
  int t = rem - i * 9;
  wq[t * 16384 + o * 128 + i] = f2bf(s);
}

// ---- kernel 3: implicit-GEMM conv. 1568 blocks (32 imgs x 49 tiles of 8x8),
// 128 threads = 2 waves. Wave computes 64 spatial x 64 cout via 16x16x32 bf16
// MFMA. A (input patch) from LDS; B (weights) from global (L2-resident). ----
__global__ __launch_bounds__(128) void conv_kernel(
    const float* __restrict__ x, const unsigned short* __restrict__ wq,
    float* __restrict__ out) {
  __shared__ unsigned short patch[100 * 136];  // [sp=ph*10+pw][ci], pad->136

  const int tid = threadIdx.x;
  const int blk = blockIdx.x;
  const int b = blk / 49;
  const int tile = blk - b * 49;
  const int th = tile / 7;
  const int tw = tile - th * 7;
  const int h0 = th * 8;
  const int w0 = tw * 8;

  // ---- stage 10x10 x 128ch input patch, fp32 -> bf16, pad value = 1.0 ----
  for (int it = tid; it < 4096; it += 128) {
    int sp = it & 127;
    if (sp >= 100) continue;
    int g = it >> 7;  // channel group of 4
    int ph = sp / 10;
    int pw = sp - ph * 10;
    int gh = h0 + ph - 1;
    int gw = w0 + pw - 1;
    unsigned int lo, hi;
    if ((unsigned)gh < 56u && (unsigned)gw < 56u) {
      const float* px = x + (((size_t)b * 128 + g * 4) * 56 + gh) * 56 + gw;
      unsigned short v0 = f2bf(px[0]);
      unsigned short v1 = f2bf(px[3136]);
      unsigned short v2 = f2bf(px[6272]);
      unsigned short v3 = f2bf(px[9408]);
      lo = (unsigned)v0 | ((unsigned)v1 << 16);
      hi = (unsigned)v2 | ((unsigned)v3 << 16);
    } else {
      lo = 0x3F803F80u;  // bf16(1.0) x2
      hi = 0x3F803F80u;
    }
    *(uint2*)&patch[sp * 136 + g * 4] = make_uint2(lo, hi);
  }
  __syncthreads();

  const int lane = tid & 63;
  const int l15 = lane & 15;
  const int quad = lane >> 4;
  const int woff = (tid >> 6) * 64;  // wave 0: cout 0..63, wave 1: 64..127

  f32x4 acc[4][4];
  #pragma unroll
  for (int mf = 0; mf < 4; ++mf)
    #pragma unroll
    for (int nf = 0; nf < 4; ++nf)
      acc[mf][nf] = (f32x4)0.f;

  const int dhb = l15 >> 3;  // spatial row within m-frag
  const int dw = l15 & 7;    // spatial col within m-frag
  const unsigned short* wbase = wq + (woff + l15) * 128 + quad * 8;
  const unsigned short* abase = &patch[(dhb * 10 + dw) * 136 + quad * 8];

  #pragma unroll
  for (int t = 0; t < 9; ++t) {
    const int kh = t / 3;
    const int kw = t - kh * 3;
    #pragma unroll
    for (int kb = 0; kb < 4; ++kb) {  // 32-channel K-blocks
      bf16x8 af[4], bfr[4];
      #pragma unroll
      for (int mf = 0; mf < 4; ++mf)
        af[mf] = *(const bf16x8*)(abase + ((mf * 2 + kh) * 10 + kw) * 136 + kb * 32);
      #pragma unroll
      for (int nf = 0; nf < 4; ++nf)
        bfr[nf] = *(const bf16x8*)(wbase + t * 16384 + nf * 2048 + kb * 32);
      #pragma unroll
      for (int mf = 0; mf < 4; ++mf)
        #pragma unroll
        for (int nf = 0; nf < 4; ++nf)
          acc[mf][nf] = __builtin_amdgcn_mfma_f32_16x16x32_bf16(
              af[mf], bfr[nf], acc[mf][nf], 0, 0, 0);
    }
  }

  // ---- epilogue: D[row=quad*4+r][col=l15]; lane's 4 accs = 4 consecutive w ----
  const int dh_off = quad >> 1;
  const int dw0 = (quad & 1) * 4;
  #pragma unroll
  for (int mf = 0; mf < 4; ++mf) {
    int h = h0 + mf * 2 + dh_off;
    #pragma unroll
    for (int nf = 0; nf < 4; ++nf) {
      int o = woff + nf * 16 + l15;
      float* p = out + (((size_t)b * 128 + o) * 56 + h) * 56 + (w0 + dw0);
      *(f32x4*)p = acc[mf][nf];
    }
  }
}

extern "C" void kernel_launch(void* const* d_in, const int* in_sizes, int n_in,
                              void* d_out, int out_size, void* d_ws, size_t ws_size,
                              hipStream_t stream) {
  const float* x = (const float*)d_in[0];       // [32,128,56,56]
  const float* w = (const float*)d_in[1];       // [5,128,128,3,3]
  const float* scales = (const float*)d_in[2];  // [5]
  float* out = (float*)d_out;                   // [32,128,56,56]

  float* c = (float*)d_ws;                                     // 5 floats
  unsigned short* wq = (unsigned short*)((char*)d_ws + 256);   // 9*128*128 bf16

  absmean_kernel<<<5, 256, 0, stream>>>(w, scales, c);
  binweight_kernel<<<576, 256, 0, stream>>>(w, c, wq);
  conv_kernel<<<1568, 128, 0, stream>>>(x, wq, out);
}

// Round 2
// 196.352 us; speedup vs baseline: 1.3917x; 1.3917x over previous
//
#include <hip/hip_runtime.h>
#include <stdint.h>

#define N_BASES 5
#define C_IN 128
#define C_OUT 128
#define WELEM (128 * 128 * 3 * 3) /* 147456 per base */

typedef __attribute__((ext_vector_type(4))) float f32x4;
typedef __attribute__((ext_vector_type(8))) short bf16x8;

__device__ __forceinline__ unsigned short f2bf(float v) {
  union { float f; uint32_t u; } un;
  un.f = v;
  uint32_t r = un.u + 0x7FFFu + ((un.u >> 16) & 1u);
  return (unsigned short)(r >> 16);
}

// ---- kernel 1: csum[n] += partial sum |w_n|  (40 blocks: 5 bases x 8 chunks) ----
__global__ __launch_bounds__(256) void absmean_part(
    const float* __restrict__ w, float* __restrict__ csum) {
  int n = blockIdx.x >> 3;
  int chunk = blockIdx.x & 7;
  const f32x4* wb = (const f32x4*)(w + (size_t)n * WELEM) + chunk * (WELEM / 32);
  float s = 0.f;
  for (int i = threadIdx.x; i < WELEM / 32; i += 256) {  // 4608 float4s / chunk
    f32x4 v = wb[i];
    s += fabsf(v.x) + fabsf(v.y) + fabsf(v.z) + fabsf(v.w);
  }
  #pragma unroll
  for (int off = 32; off > 0; off >>= 1) s += __shfl_down(s, off);
  if ((threadIdx.x & 63) == 0) atomicAdd(&csum[n], s);
}

// ---- kernel 2: W_eff[t][o][i] = sum_n coef_n*sign(w[n][o][i][t]) as bf16 ----
__global__ __launch_bounds__(256) void binweight_kernel(
    const float* __restrict__ w, const float* __restrict__ csum,
    const float* __restrict__ scales, unsigned short* __restrict__ wq) {
  int f = blockIdx.x * 256 + threadIdx.x;  // f = o*1152 + i*9 + t
  float s = 0.f;
  #pragma unroll
  for (int n = 0; n < N_BASES; ++n) {
    float cn = scales[n] * csum[n] * (1.0f / (float)WELEM);
    float v = w[n * WELEM + f];
    s += (v > 0.f) ? cn : ((v < 0.f) ? -cn : 0.f);
  }
  int o = f / 1152;
  int rem = f - o * 1152;
  int i = rem / 9;
  int t = rem - i * 9;
  wq[t * 16384 + o * 128 + i] = f2bf(s);
}

// ---- kernel 3: x[b][c][h][w] fp32 -> xp[b][hp][wp][c] bf16, pad=1.0 baked in.
// One block per (b, hp) output row. ----
__global__ __launch_bounds__(256) void prep_x(
    const float* __restrict__ x, unsigned short* __restrict__ xp) {
  int bi = blockIdx.x;
  int b = bi / 58;
  int hp = bi - b * 58;
  unsigned short* dst = xp + ((size_t)b * 58 + hp) * 58 * 128;
  int gh = hp - 1;
  if ((unsigned)gh >= 56u) {  // full pad row
    uint4 ones = make_uint4(0x3F803F80u, 0x3F803F80u, 0x3F803F80u, 0x3F803F80u);
    for (int i = threadIdx.x; i < 928; i += 256) ((uint4*)dst)[i] = ones;
    return;
  }
  __shared__ unsigned short tile[128][61];  // [c][wp], stride 61 breaks conflicts
  const float* src = x + ((size_t)b * 128 * 56 + gh) * 56;  // + c*3136 + w
  for (int i = threadIdx.x; i < 128 * 14; i += 256) {  // 14 float4 per channel row
    int c = i / 14;
    int k = i - c * 14;
    f32x4 v = *(const f32x4*)(src + (size_t)c * 3136 + k * 4);
    tile[c][1 + 4 * k + 0] = f2bf(v.x);
    tile[c][1 + 4 * k + 1] = f2bf(v.y);
    tile[c][1 + 4 * k + 2] = f2bf(v.z);
    tile[c][1 + 4 * k + 3] = f2bf(v.w);
  }
  if (threadIdx.x < 128) {  // pad columns wp=0, wp=57
    tile[threadIdx.x][0] = 0x3F80;
    tile[threadIdx.x][57] = 0x3F80;
  }
  __syncthreads();
  for (int i = threadIdx.x; i < 928; i += 256) {  // 58 wp x 16 c8-chunks
    int wp = i >> 4;
    int c8 = i & 15;
    union { uint4 q; unsigned short h[8]; } u;
    #pragma unroll
    for (int j = 0; j < 8; ++j) u.h[j] = tile[c8 * 8 + j][wp];
    *(uint4*)(dst + (size_t)wp * 128 + c8 * 8) = u.q;
  }
}

// ---- kernel 4: implicit-GEMM conv. blk = tile*32 + b (image->XCD pinning).
// 128 threads = 2 waves; wave = 64 spatial x 64 cout via 16x16x32 bf16 MFMA. ----
__global__ __launch_bounds__(128) void conv_kernel(
    const unsigned short* __restrict__ xp, const unsigned short* __restrict__ wq,
    float* __restrict__ out) {
  __shared__ unsigned short patch[100 * 136];  // [sp=ph*10+pw][ci], pad->136

  const int tid = threadIdx.x;
  const int blk = blockIdx.x;
  const int b = blk & 31;
  const int tile = blk >> 5;
  const int th = tile / 7;
  const int tw = tile - th * 7;
  const int h0 = th * 8;
  const int w0 = tw * 8;

  // ---- stage 10 rows x (10 px x 128 ch) bf16, fully coalesced 16B chunks ----
  const size_t rowstride = 58 * 128;
  const unsigned short* base = xp + ((size_t)b * 58 + h0) * rowstride + (size_t)w0 * 128;
  for (int i = tid; i < 1600; i += 128) {  // 10 rows x 160 chunks of 16B
    int row = i / 160;
    int off = i - row * 160;  // off*8 u16 = pw*128 + c8*8
    uint4 v = *(const uint4*)(base + row * rowstride + (size_t)off * 8);
    int sp = row * 10 + (off >> 4);
    int c8 = off & 15;
    *(uint4*)&patch[sp * 136 + c8 * 8] = v;
  }
  __syncthreads();

  const int lane = tid & 63;
  const int l15 = lane & 15;
  const int quad = lane >> 4;
  const int woff = (tid >> 6) * 64;  // wave 0: cout 0..63, wave 1: 64..127

  f32x4 acc[4][4];
  #pragma unroll
  for (int mf = 0; mf < 4; ++mf)
    #pragma unroll
    for (int nf = 0; nf < 4; ++nf)
      acc[mf][nf] = (f32x4)0.f;

  const int dhb = l15 >> 3;  // spatial row within m-frag
  const int dw = l15 & 7;    // spatial col within m-frag
  const unsigned short* wbase = wq + (woff + l15) * 128 + quad * 8;
  const unsigned short* abase = &patch[(dhb * 10 + dw) * 136 + quad * 8];

  #pragma unroll
  for (int t = 0; t < 9; ++t) {
    const int kh = t / 3;
    const int kw = t - kh * 3;
    #pragma unroll
    for (int kb = 0; kb < 4; ++kb) {  // 32-channel K-blocks
      bf16x8 af[4], bfr[4];
      #pragma unroll
      for (int mf = 0; mf < 4; ++mf)
        af[mf] = *(const bf16x8*)(abase + ((mf * 2 + kh) * 10 + kw) * 136 + kb * 32);
      #pragma unroll
      for (int nf = 0; nf < 4; ++nf)
        bfr[nf] = *(const bf16x8*)(wbase + t * 16384 + nf * 2048 + kb * 32);
      #pragma unroll
      for (int mf = 0; mf < 4; ++mf)
        #pragma unroll
        for (int nf = 0; nf < 4; ++nf)
          acc[mf][nf] = __builtin_amdgcn_mfma_f32_16x16x32_bf16(
              af[mf], bfr[nf], acc[mf][nf], 0, 0, 0);
    }
  }

  // ---- epilogue: D[row=quad*4+r][col=l15]; lane's 4 accs = 4 consecutive w ----
  const int dh_off = quad >> 1;
  const int dw0 = (quad & 1) * 4;
  #pragma unroll
  for (int mf = 0; mf < 4; ++mf) {
    int h = h0 + mf * 2 + dh_off;
    #pragma unroll
    for (int nf = 0; nf < 4; ++nf) {
      int o = woff + nf * 16 + l15;
      float* p = out + (((size_t)b * 128 + o) * 56 + h) * 56 + (w0 + dw0);
      *(f32x4*)p = acc[mf][nf];
    }
  }
}

extern "C" void kernel_launch(void* const* d_in, const int* in_sizes, int n_in,
                              void* d_out, int out_size, void* d_ws, size_t ws_size,
                              hipStream_t stream) {
  const float* x = (const float*)d_in[0];       // [32,128,56,56]
  const float* w = (const float*)d_in[1];       // [5,128,128,3,3]
  const float* scales = (const float*)d_in[2];  // [5]
  float* out = (float*)d_out;                   // [32,128,56,56]

  float* csum = (float*)d_ws;                                       // 5 floats
  unsigned short* wq = (unsigned short*)((char*)d_ws + 256);        // 9*128*128 bf16
  unsigned short* xpad = (unsigned short*)((char*)d_ws + 512 * 1024); // 32*58*58*128 bf16 (~27.6 MB)

  hipMemsetAsync(csum, 0, 5 * sizeof(float), stream);
  absmean_part<<<40, 256, 0, stream>>>(w, csum);
  binweight_kernel<<<576, 256, 0, stream>>>(w, csum, scales, wq);
  prep_x<<<32 * 58, 256, 0, stream>>>(x, xpad);
  conv_kernel<<<49 * 32, 128, 0, stream>>>(xpad, wq, out);
}

// Round 3
// 190.990 us; speedup vs baseline: 1.4307x; 1.0281x over previous
//
#include <hip/hip_runtime.h>
#include <stdint.h>

#define N_BASES 5
#define WELEM (128 * 128 * 3 * 3) /* 147456 per base */

typedef __attribute__((ext_vector_type(4))) float f32x4;
typedef __attribute__((ext_vector_type(8))) short bf16x8;

__device__ __forceinline__ unsigned short f2bf(float v) {
  union { float f; uint32_t u; } un;
  un.f = v;
  uint32_t r = un.u + 0x7FFFu + ((un.u >> 16) & 1u);
  return (unsigned short)(r >> 16);
}

// ---- kernel 1 (fused): blocks 0..1855 = x NCHW fp32 -> padded NHWC bf16;
//      blocks 1856..2175 = per-(base,chunk) |w| partial sums (no memset needed).
__global__ __launch_bounds__(256) void prep_fused(
    const float* __restrict__ x, const float* __restrict__ w,
    unsigned short* __restrict__ xp, float* __restrict__ csum_part) {
  int bi = blockIdx.x;
  if (bi >= 1856) {
    // ---- absmean partials: 5 bases x 64 chunks of 2304 floats ----
    int id = bi - 1856;
    int n = id >> 6;
    int chunk = id & 63;
    const f32x4* wb = (const f32x4*)(w + (size_t)n * WELEM + chunk * 2304);
    float s = 0.f;
    for (int i = threadIdx.x; i < 576; i += 256) {
      f32x4 v = wb[i];
      s += fabsf(v.x) + fabsf(v.y) + fabsf(v.z) + fabsf(v.w);
    }
    #pragma unroll
    for (int off = 32; off > 0; off >>= 1) s += __shfl_down(s, off);
    __shared__ float red[4];
    if ((threadIdx.x & 63) == 0) red[threadIdx.x >> 6] = s;
    __syncthreads();
    if (threadIdx.x == 0) csum_part[id] = red[0] + red[1] + red[2] + red[3];
    return;
  }
  int b = bi / 58;
  int hp = bi - b * 58;
  unsigned short* dst = xp + ((size_t)b * 58 + hp) * 58 * 128;
  int gh = hp - 1;
  if ((unsigned)gh >= 56u) {  // full pad row
    uint4 ones = make_uint4(0x3F803F80u, 0x3F803F80u, 0x3F803F80u, 0x3F803F80u);
    for (int i = threadIdx.x; i < 928; i += 256) ((uint4*)dst)[i] = ones;
    return;
  }
  __shared__ unsigned short tile[128][61];  // [c][wp], stride 61 breaks conflicts
  const float* src = x + ((size_t)b * 128 * 56 + gh) * 56;
  for (int i = threadIdx.x; i < 128 * 14; i += 256) {
    int c = i / 14;
    int k = i - c * 14;
    f32x4 v = *(const f32x4*)(src + (size_t)c * 3136 + k * 4);
    tile[c][1 + 4 * k + 0] = f2bf(v.x);
    tile[c][1 + 4 * k + 1] = f2bf(v.y);
    tile[c][1 + 4 * k + 2] = f2bf(v.z);
    tile[c][1 + 4 * k + 3] = f2bf(v.w);
  }
  if (threadIdx.x < 128) {
    tile[threadIdx.x][0] = 0x3F80;
    tile[threadIdx.x][57] = 0x3F80;
  }
  __syncthreads();
  for (int i = threadIdx.x; i < 928; i += 256) {
    int wp = i >> 4;
    int c8 = i & 15;
    union { uint4 q; unsigned short h[8]; } u;
    #pragma unroll
    for (int j = 0; j < 8; ++j) u.h[j] = tile[c8 * 8 + j][wp];
    *(uint4*)(dst + (size_t)wp * 128 + c8 * 8) = u.q;
  }
}

// ---- kernel 2: W_eff[t][o][i] = sum_n coef_n*sign(w[n][o][i][t]) as bf16 ----
__global__ __launch_bounds__(256) void binweight_kernel(
    const float* __restrict__ w, const float* __restrict__ csum_part,
    const float* __restrict__ scales, unsigned short* __restrict__ wq) {
  __shared__ float parts[320];
  __shared__ float coef[N_BASES];
  for (int i = threadIdx.x; i < 320; i += 256) parts[i] = csum_part[i];
  __syncthreads();
  if (threadIdx.x < N_BASES) {
    float s = 0.f;
    #pragma unroll 8
    for (int k = 0; k < 64; ++k) s += parts[threadIdx.x * 64 + k];
    coef[threadIdx.x] = scales[threadIdx.x] * s * (1.0f / (float)WELEM);
  }
  __syncthreads();
  int f = blockIdx.x * 256 + threadIdx.x;  // f = o*1152 + i*9 + t
  float s = 0.f;
  #pragma unroll
  for (int n = 0; n < N_BASES; ++n) {
    float cn = coef[n];
    float v = w[n * WELEM + f];
    s += (v > 0.f) ? cn : ((v < 0.f) ? -cn : 0.f);
  }
  int o = f / 1152;
  int rem = f - o * 1152;
  int i = rem / 9;
  int t = rem - i * 9;
  wq[t * 16384 + o * 128 + i] = f2bf(s);
}

// ---- kernel 3: implicit-GEMM conv. Block = 2 images x 8x8 spatial x 128 cout,
// 256 threads = 4 waves; wave w handles couts w*32..w*32+31 for BOTH images.
// Each B fragment feeds 16 MFMAs; 1-deep B prefetch hides L2 latency. ----
__global__ __launch_bounds__(256, 2) void conv_kernel(
    const unsigned short* __restrict__ xp, const unsigned short* __restrict__ wq,
    float* __restrict__ out) {
  __shared__ unsigned short patch[2][13600];  // [img][sp=ph*10+pw][ci], stride 136

  const int tid = threadIdx.x;
  const int blk = blockIdx.x;
  const int pair = blk & 15;  // images pair, pair+16
  const int tile = blk >> 4;
  const int th = tile / 7;
  const int tw = tile - th * 7;
  const int h0 = th * 8;
  const int w0 = tw * 8;

  // ---- stage 2 x (10 rows x 10 px x 128 ch) bf16, coalesced 16B chunks ----
  const size_t rowstride = 58 * 128;
  #pragma unroll
  for (int img = 0; img < 2; ++img) {
    int b = pair + img * 16;
    const unsigned short* base =
        xp + ((size_t)b * 58 + h0) * rowstride + (size_t)w0 * 128;
    for (int i = tid; i < 1600; i += 256) {  // 10 rows x 160 chunks of 16B
      int row = i / 160;
      int off = i - row * 160;
      uint4 v = *(const uint4*)(base + row * rowstride + (size_t)off * 8);
      int sp = row * 10 + (off >> 4);
      int c8 = off & 15;
      *(uint4*)&patch[img][sp * 136 + c8 * 8] = v;
    }
  }
  __syncthreads();

  const int lane = tid & 63;
  const int wave = tid >> 6;  // cout block: wave*32
  const int l15 = lane & 15;
  const int quad = lane >> 4;

  f32x4 acc[2][4][2];
  #pragma unroll
  for (int img = 0; img < 2; ++img)
    #pragma unroll
    for (int mf = 0; mf < 4; ++mf)
      #pragma unroll
      for (int nf = 0; nf < 2; ++nf)
        acc[img][mf][nf] = (f32x4)0.f;

  const int dhb = l15 >> 3;
  const int dw = l15 & 7;
  const unsigned short* wbase = wq + ((wave << 5) + l15) * 128 + quad * 8;
  const unsigned short* abase0 = &patch[0][(dhb * 10 + dw) * 136 + quad * 8];
  const unsigned short* abase1 = &patch[1][(dhb * 10 + dw) * 136 + quad * 8];

  auto loadB = [&](int li, bf16x8* dst) {
    const int t = li >> 2;
    const int kb = li & 3;
    const unsigned short* p = wbase + t * 16384 + kb * 32;
    dst[0] = *(const bf16x8*)p;
    dst[1] = *(const bf16x8*)(p + 2048);
  };

  bf16x8 bfr[2][2];
  loadB(0, bfr[0]);

  #pragma unroll
  for (int li = 0; li < 36; ++li) {  // li = t*4 + kb
    const int cur = li & 1;
    const int t = li >> 2;
    const int kb = li & 3;
    const int kh = t / 3;
    const int kw = t - kh * 3;
    bf16x8 af[2][4];
    #pragma unroll
    for (int mf = 0; mf < 4; ++mf) {
      const int poff = ((mf * 2 + kh) * 10 + kw) * 136 + kb * 32;
      af[0][mf] = *(const bf16x8*)(abase0 + poff);
      af[1][mf] = *(const bf16x8*)(abase1 + poff);
    }
    if (li < 35) loadB(li + 1, bfr[cur ^ 1]);
    #pragma unroll
    for (int img = 0; img < 2; ++img)
      #pragma unroll
      for (int mf = 0; mf < 4; ++mf)
        #pragma unroll
        for (int nf = 0; nf < 2; ++nf)
          acc[img][mf][nf] = __builtin_amdgcn_mfma_f32_16x16x32_bf16(
              af[img][mf], bfr[cur][nf], acc[img][mf][nf], 0, 0, 0);
  }

  // ---- epilogue: D[row=quad*4+r][col=l15]; lane's 4 accs = 4 consecutive w ----
  const int dh_off = quad >> 1;
  const int dw0 = (quad & 1) * 4;
  #pragma unroll
  for (int img = 0; img < 2; ++img) {
    int b = pair + img * 16;
    #pragma unroll
    for (int mf = 0; mf < 4; ++mf) {
      int h = h0 + mf * 2 + dh_off;
      #pragma unroll
      for (int nf = 0; nf < 2; ++nf) {
        int o = (wave << 5) + nf * 16 + l15;
        float* p = out + (((size_t)b * 128 + o) * 56 + h) * 56 + (w0 + dw0);
        *(f32x4*)p = acc[img][mf][nf];
      }
    }
  }
}

extern "C" void kernel_launch(void* const* d_in, const int* in_sizes, int n_in,
                              void* d_out, int out_size, void* d_ws, size_t ws_size,
                              hipStream_t stream) {
  const float* x = (const float*)d_in[0];       // [32,128,56,56]
  const float* w = (const float*)d_in[1];       // [5,128,128,3,3]
  const float* scales = (const float*)d_in[2];  // [5]
  float* out = (float*)d_out;                   // [32,128,56,56]

  float* csum_part = (float*)d_ws;                                   // 320 floats
  unsigned short* wq = (unsigned short*)((char*)d_ws + 4096);        // 9*128*128 bf16
  unsigned short* xpad = (unsigned short*)((char*)d_ws + 512 * 1024); // 32*58*58*128 bf16

  prep_fused<<<1856 + 320, 256, 0, stream>>>(x, w, xpad, csum_part);
  binweight_kernel<<<576, 256, 0, stream>>>(w, csum_part, scales, wq);
  conv_kernel<<<49 * 16, 256, 0, stream>>>(xpad, wq, out);
}

// Round 4
// 153.567 us; speedup vs baseline: 1.7794x; 1.2437x over previous
//
#include <hip/hip_runtime.h>
#include <stdint.h>

#define N_BASES 5
#define WELEM (128 * 128 * 3 * 3) /* 147456 per base */

typedef __attribute__((ext_vector_type(4))) float f32x4;
typedef __attribute__((ext_vector_type(8))) short bf16x8;

__device__ __forceinline__ unsigned short f2bf(float v) {
  union { float f; uint32_t u; } un;
  un.f = v;
  uint32_t r = un.u + 0x7FFFu + ((un.u >> 16) & 1u);
  return (unsigned short)(r >> 16);
}

__device__ __forceinline__ void glds16(const void* g, void* l) {
  __builtin_amdgcn_global_load_lds(
      (const __attribute__((address_space(1))) void*)g,
      (__attribute__((address_space(3))) void*)l, 16, 0, 0);
}

// ---- kernel 1 (fused): blocks 0..1855 = x NCHW fp32 -> padded NHWC bf16;
//      blocks 1856..2175 = per-(base,chunk) |w| partial sums.
__global__ __launch_bounds__(256) void prep_fused(
    const float* __restrict__ x, const float* __restrict__ w,
    unsigned short* __restrict__ xp, float* __restrict__ csum_part) {
  int bi = blockIdx.x;
  if (bi >= 1856) {
    int id = bi - 1856;
    int n = id >> 6;
    int chunk = id & 63;
    const f32x4* wb = (const f32x4*)(w + (size_t)n * WELEM + chunk * 2304);
    float s = 0.f;
    for (int i = threadIdx.x; i < 576; i += 256) {
      f32x4 v = wb[i];
      s += fabsf(v.x) + fabsf(v.y) + fabsf(v.z) + fabsf(v.w);
    }
    #pragma unroll
    for (int off = 32; off > 0; off >>= 1) s += __shfl_down(s, off);
    __shared__ float red[4];
    if ((threadIdx.x & 63) == 0) red[threadIdx.x >> 6] = s;
    __syncthreads();
    if (threadIdx.x == 0) csum_part[id] = red[0] + red[1] + red[2] + red[3];
    return;
  }
  int b = bi / 58;
  int hp = bi - b * 58;
  unsigned short* dst = xp + ((size_t)b * 58 + hp) * 58 * 128;
  int gh = hp - 1;
  if ((unsigned)gh >= 56u) {  // full pad row
    uint4 ones = make_uint4(0x3F803F80u, 0x3F803F80u, 0x3F803F80u, 0x3F803F80u);
    for (int i = threadIdx.x; i < 928; i += 256) ((uint4*)dst)[i] = ones;
    return;
  }
  __shared__ unsigned short tile[128][61];
  const float* src = x + ((size_t)b * 128 * 56 + gh) * 56;
  for (int i = threadIdx.x; i < 128 * 14; i += 256) {
    int c = i / 14;
    int k = i - c * 14;
    f32x4 v = *(const f32x4*)(src + (size_t)c * 3136 + k * 4);
    tile[c][1 + 4 * k + 0] = f2bf(v.x);
    tile[c][1 + 4 * k + 1] = f2bf(v.y);
    tile[c][1 + 4 * k + 2] = f2bf(v.z);
    tile[c][1 + 4 * k + 3] = f2bf(v.w);
  }
  if (threadIdx.x < 128) {
    tile[threadIdx.x][0] = 0x3F80;
    tile[threadIdx.x][57] = 0x3F80;
  }
  __syncthreads();
  for (int i = threadIdx.x; i < 928; i += 256) {
    int wp = i >> 4;
    int c8 = i & 15;
    union { uint4 q; unsigned short h[8]; } u;
    #pragma unroll
    for (int j = 0; j < 8; ++j) u.h[j] = tile[c8 * 8 + j][wp];
    *(uint4*)(dst + (size_t)wp * 128 + c8 * 8) = u.q;
  }
}

// ---- kernel 2: W_eff -> bf16, swizzled layout for direct global_load_lds:
// stage s = t*2 + (i>>6) holds 128o x 64ch; element (o,i,t) ->
// wq[s*8192 + o*64 + ((c8 ^ (o&7)))*8 + (i&7)], c8 = (i>>3)&7. ----
__global__ __launch_bounds__(256) void binweight_kernel(
    const float* __restrict__ w, const float* __restrict__ csum_part,
    const float* __restrict__ scales, unsigned short* __restrict__ wq) {
  __shared__ float parts[320];
  __shared__ float coef[N_BASES];
  for (int i = threadIdx.x; i < 320; i += 256) parts[i] = csum_part[i];
  __syncthreads();
  if (threadIdx.x < N_BASES) {
    float s = 0.f;
    #pragma unroll 8
    for (int k = 0; k < 64; ++k) s += parts[threadIdx.x * 64 + k];
    coef[threadIdx.x] = scales[threadIdx.x] * s * (1.0f / (float)WELEM);
  }
  __syncthreads();
  int f = blockIdx.x * 256 + threadIdx.x;  // f = o*1152 + i*9 + t
  float s = 0.f;
  #pragma unroll
  for (int n = 0; n < N_BASES; ++n) {
    float cn = coef[n];
    float v = w[n * WELEM + f];
    s += (v > 0.f) ? cn : ((v < 0.f) ? -cn : 0.f);
  }
  int o = f / 1152;
  int rem = f - o * 1152;
  int i = rem / 9;
  int t = rem - i * 9;
  int half = i >> 6;
  int c8 = (i >> 3) & 7;
  int e = i & 7;
  wq[(size_t)(t * 2 + half) * 8192 + o * 64 + ((c8 ^ (o & 7)) << 3) + e] = f2bf(s);
}

// ---- kernel 3: m97-style implicit-GEMM conv.
// Block: 2 imgs x (4h x 16w) spatial x 128 cout. 256 thr = 4 waves;
// wave (img = w>>1, nhalf = w&1) computes M=64 x N=64.
// A: patch in LDS (XOR-swizzled, staged once). B: 16KB half-tap tiles staged
// via global_load_lds from pre-swizzled wq. 8 ds_read_b128 : 16 MFMA per kb. ----
__global__ __launch_bounds__(256, 2) void conv_kernel(
    const unsigned short* __restrict__ xp, const unsigned short* __restrict__ wq,
    float* __restrict__ out) {
  __shared__ unsigned short patch[27648];  // 2 img x 108 sp x 128 ch (55.3 KB)
  __shared__ unsigned short btile[8192];   // 128 o x 64 ch (16 KB)

  const int tid = threadIdx.x;
  const int blk = blockIdx.x;
  const int pair = blk & 15;      // imgs pair, pair+16
  const int tileIdx = blk >> 4;   // 0..55 = hi*4 + wi
  const int hi = tileIdx >> 2;
  const int wi = tileIdx & 3;
  const int h0 = hi * 4;
  const int w0 = (wi == 3) ? 40 : wi * 16;

  // ---- stage patch: 2 x 108 sp (6 rows x 18 px) x 16 chunks, swizzled ----
  const size_t rowstride = 58 * 128;
  for (int i = tid; i < 3456; i += 256) {
    int img = i / 1728;
    int r = i - img * 1728;
    int sp = r >> 4;
    int c16 = r & 15;
    int ph = sp / 18;
    int pw = sp - ph * 18;
    int b = pair + img * 16;
    const unsigned short* gp = xp + ((size_t)b * 58 + (h0 + ph)) * rowstride +
                               (size_t)(w0 + pw) * 128 + c16 * 8;
    uint4 v = *(const uint4*)gp;
    *(uint4*)&patch[img * 13824 + sp * 128 + ((c16 ^ (sp & 7)) << 3)] = v;
  }

  const int lane = tid & 63;
  const int wave = tid >> 6;
  const int img = wave >> 1;
  const int nh = wave & 1;
  const int l15 = lane & 15;
  const int quad = lane >> 4;

  f32x4 acc[4][4];
  #pragma unroll
  for (int mf = 0; mf < 4; ++mf)
    #pragma unroll
    for (int nf = 0; nf < 4; ++nf) acc[mf][nf] = (f32x4)0.f;

  const unsigned short* pb = &patch[img * 13824];

  #pragma unroll
  for (int t = 0; t < 9; ++t) {
    const int kh = t / 3;
    const int kw = t - kh * 3;
    int sp_mf[4];
    #pragma unroll
    for (int mf = 0; mf < 4; ++mf) sp_mf[mf] = (mf + kh) * 18 + (l15 + kw);
    #pragma unroll
    for (int half = 0; half < 2; ++half) {
      __syncthreads();  // previous btile reads complete
      {
        const unsigned short* g =
            wq + (size_t)(t * 2 + half) * 8192 + wave * 2048 + lane * 8;
        unsigned short* l = &btile[wave * 2048];
        #pragma unroll
        for (int j = 0; j < 4; ++j) glds16(g + j * 512, l + j * 512);
      }
      __syncthreads();  // staging complete (vmcnt drained at barrier)
      #pragma unroll
      for (int kk = 0; kk < 2; ++kk) {
        const int kb = half * 2 + kk;
        bf16x8 af[4], bf[4];
        #pragma unroll
        for (int mf = 0; mf < 4; ++mf) {
          int sp = sp_mf[mf];
          af[mf] = *(const bf16x8*)&pb[sp * 128 + (((kb * 4 + quad) ^ (sp & 7)) << 3)];
        }
        #pragma unroll
        for (int nf = 0; nf < 4; ++nf) {
          int o = nh * 64 + nf * 16 + l15;
          bf[nf] = *(const bf16x8*)&btile[o * 64 + (((kk * 4 + quad) ^ (o & 7)) << 3)];
        }
        #pragma unroll
        for (int mf = 0; mf < 4; ++mf)
          #pragma unroll
          for (int nf = 0; nf < 4; ++nf)
            acc[mf][nf] = __builtin_amdgcn_mfma_f32_16x16x32_bf16(
                af[mf], bf[nf], acc[mf][nf], 0, 0, 0);
      }
    }
  }

  // ---- epilogue: D row = quad*4+r = w-offset, col = l15 = cout-low.
  // lane's f32x4 = w0+quad*4 .. +3 at h = h0+mf: full 64-B sectors per (o,h). ----
  const int b = pair + img * 16;
  #pragma unroll
  for (int mf = 0; mf < 4; ++mf) {
    int h = h0 + mf;
    #pragma unroll
    for (int nf = 0; nf < 4; ++nf) {
      int o = nh * 64 + nf * 16 + l15;
      float* p = out + (((size_t)b * 128 + o) * 56 + h) * 56 + w0 + quad * 4;
      *(f32x4*)p = acc[mf][nf];
    }
  }
}

extern "C" void kernel_launch(void* const* d_in, const int* in_sizes, int n_in,
                              void* d_out, int out_size, void* d_ws, size_t ws_size,
                              hipStream_t stream) {
  const float* x = (const float*)d_in[0];       // [32,128,56,56]
  const float* w = (const float*)d_in[1];       // [5,128,128,3,3]
  const float* scales = (const float*)d_in[2];  // [5]
  float* out = (float*)d_out;                   // [32,128,56,56]

  float* csum_part = (float*)d_ws;                                    // 320 floats
  unsigned short* wq = (unsigned short*)((char*)d_ws + 4096);         // 18*8192 bf16
  unsigned short* xpad = (unsigned short*)((char*)d_ws + 512 * 1024); // 32*58*58*128 bf16

  prep_fused<<<1856 + 320, 256, 0, stream>>>(x, w, xpad, csum_part);
  binweight_kernel<<<576, 256, 0, stream>>>(w, csum_part, scales, wq);
  conv_kernel<<<56 * 16, 256, 0, stream>>>(xpad, wq, out);
}